// Round 1
// baseline (140.035 us; speedup 1.0000x reference)
//
#include <hip/hip_runtime.h>
#include <hip/hip_bf16.h>
#include <stdint.h>

typedef __bf16 bf16_t;
typedef __bf16 bf16x8 __attribute__((ext_vector_type(8)));
typedef float f32x4 __attribute__((ext_vector_type(4)));

#define E_DIM 1024
#define S_DIM 8192

// ---- global -> LDS direct load, 16 B per lane (CK-style addrspace casts) ----
__device__ __forceinline__ void gload_lds16(const void* g, void* l) {
  using gptr_t = const __attribute__((address_space(1))) void*;
  using lptr_t = __attribute__((address_space(3))) void*;
  gptr_t gp = (gptr_t)(uintptr_t)g;
  lptr_t lp = (lptr_t)(uint32_t)(uintptr_t)l;
  __builtin_amdgcn_global_load_lds(gp, lp, 16, 0, 0);
}

// ---- fp32 -> bf16 conversion, 8 elems/thread ----
__global__ __launch_bounds__(256) void cvt_f32_bf16(const float* __restrict__ src,
                                                    bf16_t* __restrict__ dst, int n8) {
  int i = blockIdx.x * 256 + threadIdx.x;
  if (i < n8) {
    const float4* s = reinterpret_cast<const float4*>(src) + (size_t)i * 2;
    float4 a = s[0], b = s[1];
    bf16x8 o;
    o[0] = (bf16_t)a.x; o[1] = (bf16_t)a.y; o[2] = (bf16_t)a.z; o[3] = (bf16_t)a.w;
    o[4] = (bf16_t)b.x; o[5] = (bf16_t)b.y; o[6] = (bf16_t)b.z; o[7] = (bf16_t)b.w;
    *reinterpret_cast<bf16x8*>(dst + (size_t)i * 8) = o;
  }
}

// ---- C = A * B^T + bias, A:[M][1024] bf16, B:[N][1024] bf16, C fp32 [M][ldc]
// MODE 0: C = acc + bias (bias0 for col<1024, bias1 for col>=1024)
// MODE 1: C = sigmoid(acc + bias0) * (*cptr)
template <int MODE>
__global__ __launch_bounds__(256) void gemm_bt(const bf16_t* __restrict__ A,
                                               const bf16_t* __restrict__ B,
                                               float* __restrict__ C,
                                               const float* __restrict__ bias0,
                                               const float* __restrict__ bias1,
                                               const float* __restrict__ cptr, int ldc) {
  __shared__ bf16_t lA[128 * 32];
  __shared__ bf16_t lB[128 * 32];

  const int tid = threadIdx.x;
  const int wv = tid >> 6;
  const int lane = tid & 63;
  const int m0 = blockIdx.y * 128;
  const int n0 = blockIdx.x * 128;
  const int wr = wv >> 1;  // wave row (0..1), 64 rows each
  const int wc = wv & 1;   // wave col (0..1), 64 cols each

  f32x4 acc[4][4];
#pragma unroll
  for (int i = 0; i < 4; ++i)
#pragma unroll
    for (int j = 0; j < 4; ++j) acc[i][j] = (f32x4){0.f, 0.f, 0.f, 0.f};

  // staging: tile is 128 rows x 32 k.  8 wave-chunks of 16 rows (1 KB each);
  // wave wv does chunks wv and wv+4.  lane l -> row = chunk*16 + l/4, k = (l%4)*8.
  const int srow = wv * 16 + (lane >> 2);
  const int skk = (lane & 3) * 8;
  const bf16_t* gA0 = A + (size_t)(m0 + srow) * E_DIM + skk;
  const bf16_t* gA1 = gA0 + (size_t)64 * E_DIM;
  const bf16_t* gB0 = B + (size_t)(n0 + srow) * E_DIM + skk;
  const bf16_t* gB1 = gB0 + (size_t)64 * E_DIM;
  bf16_t* lA0 = &lA[wv * 512];
  bf16_t* lA1 = &lA[(wv + 4) * 512];
  bf16_t* lB0 = &lB[wv * 512];
  bf16_t* lB1 = &lB[(wv + 4) * 512];

  const int frow = lane & 15;
  const int fk = (lane >> 4) * 8;

  for (int k0 = 0; k0 < E_DIM; k0 += 32) {
    gload_lds16(gA0 + k0, lA0);
    gload_lds16(gA1 + k0, lA1);
    gload_lds16(gB0 + k0, lB0);
    gload_lds16(gB1 + k0, lB1);
    __syncthreads();  // drains vmcnt for all waves' global_load_lds

    bf16x8 af[4], bfr[4];
#pragma unroll
    for (int m = 0; m < 4; ++m)
      af[m] = *reinterpret_cast<const bf16x8*>(&lA[(wr * 64 + m * 16 + frow) * 32 + fk]);
#pragma unroll
    for (int n = 0; n < 4; ++n)
      bfr[n] = *reinterpret_cast<const bf16x8*>(&lB[(wc * 64 + n * 16 + frow) * 32 + fk]);
#pragma unroll
    for (int m = 0; m < 4; ++m)
#pragma unroll
      for (int n = 0; n < 4; ++n)
        acc[m][n] = __builtin_amdgcn_mfma_f32_16x16x32_bf16(af[m], bfr[n], acc[m][n], 0, 0, 0);
    __syncthreads();  // before next stage overwrites LDS
  }

  float cval = 0.f;
  if (MODE == 1) cval = cptr[0];
  const int crow = (lane >> 4) * 4;
  const int ccol = lane & 15;
#pragma unroll
  for (int n = 0; n < 4; ++n) {
    const int col = n0 + wc * 64 + n * 16 + ccol;
    const float bs = (bias1 == nullptr || col < 1024) ? bias0[col] : bias1[col - 1024];
#pragma unroll
    for (int m = 0; m < 4; ++m) {
      const int row = m0 + wr * 64 + m * 16 + crow;
#pragma unroll
      for (int r = 0; r < 4; ++r) {
        float v = acc[m][n][r] + bs;
        if (MODE == 1) v = cval / (1.f + __expf(-v));
        C[(size_t)(row + r) * ldc + col] = v;
      }
    }
  }
}

// ---- partial softmax-denominator / numerator over 32-row chunks ----
// KV: [8192][2048] fp32 (cols 0..1023 = K, 1024..2047 = V)
// part: [256][2][1024] fp32
__global__ __launch_bounds__(256) void reduce_kv(const float* __restrict__ KV,
                                                 float* __restrict__ part) {
  const int b = blockIdx.x;  // 256 blocks, 32 rows each
  const int t = threadIdx.x;
  float den[4] = {0.f, 0.f, 0.f, 0.f};
  float num[4] = {0.f, 0.f, 0.f, 0.f};
  const float* base = KV + (size_t)b * 32 * 2048;
  for (int r = 0; r < 32; ++r) {
    const float* rowp = base + (size_t)r * 2048;
#pragma unroll
    for (int j = 0; j < 4; ++j) {
      float k = rowp[t + j * 256];
      float v = rowp[t + j * 256 + 1024];
      float e = __expf(k);  // |K| small: no max-subtraction needed in fp32
      den[j] += e;
      num[j] += e * v;
    }
  }
#pragma unroll
  for (int j = 0; j < 4; ++j) {
    part[(size_t)b * 2048 + t + j * 256] = den[j];
    part[(size_t)b * 2048 + 1024 + t + j * 256] = num[j];
  }
}

// ---- finish: per-column num/den, then sum over 1024 columns -> 4 partials ----
__global__ __launch_bounds__(256) void finalize1(const float* __restrict__ part,
                                                 float* __restrict__ cpart) {
  const int col = blockIdx.x * 256 + threadIdx.x;
  float den = 0.f, num = 0.f;
  for (int c = 0; c < 256; ++c) {
    den += part[(size_t)c * 2048 + col];
    num += part[(size_t)c * 2048 + 1024 + col];
  }
  float val = num / den;
  __shared__ float red[256];
  red[threadIdx.x] = val;
  __syncthreads();
  for (int s = 128; s > 0; s >>= 1) {
    if (threadIdx.x < s) red[threadIdx.x] += red[threadIdx.x + s];
    __syncthreads();
  }
  if (threadIdx.x == 0) cpart[blockIdx.x] = red[0];
}

__global__ void finalize2(const float* __restrict__ cpart, float* __restrict__ cval) {
  if (threadIdx.x == 0) cval[0] = cpart[0] + cpart[1] + cpart[2] + cpart[3];
}

extern "C" void kernel_launch(void* const* d_in, const int* in_sizes, int n_in,
                              void* d_out, int out_size, void* d_ws, size_t ws_size,
                              hipStream_t stream) {
  const float* q = (const float*)d_in[0];
  const float* Wq = (const float*)d_in[1];
  const float* bq = (const float*)d_in[2];
  const float* Wk = (const float*)d_in[3];
  const float* bk = (const float*)d_in[4];
  const float* Wv = (const float*)d_in[5];
  const float* bv = (const float*)d_in[6];
  float* out = (float*)d_out;

  char* ws = (char*)d_ws;
  float* KV = (float*)ws;                                   // 64 MB: [8192][2048]
  bf16_t* qb = (bf16_t*)(ws + (size_t)64 * 1024 * 1024);    // 16 MB: q in bf16
  bf16_t* Wb = (bf16_t*)(ws + (size_t)80 * 1024 * 1024);    // 6 MB: [Wk;Wv;Wq] bf16
  float* part = (float*)(ws + (size_t)86 * 1024 * 1024);    // 2 MB
  float* cpart = (float*)(ws + (size_t)88 * 1024 * 1024);   // 16 B
  float* cval = cpart + 4;

  cvt_f32_bf16<<<4096, 256, 0, stream>>>(q, qb, 1048576);
  cvt_f32_bf16<<<512, 256, 0, stream>>>(Wk, Wb, 131072);
  cvt_f32_bf16<<<512, 256, 0, stream>>>(Wv, Wb + 1048576, 131072);
  cvt_f32_bf16<<<512, 256, 0, stream>>>(Wq, Wb + 2097152, 131072);

  // K and V in one GEMM: B = [Wk; Wv], N = 2048
  gemm_bt<0><<<dim3(16, 64), 256, 0, stream>>>(qb, Wb, KV, bk, bv, nullptr, 2048);

  reduce_kv<<<256, 256, 0, stream>>>(KV, part);
  finalize1<<<4, 256, 0, stream>>>(part, cpart);
  finalize2<<<1, 64, 0, stream>>>(cpart, cval);

  // Y = sigmoid(q @ Wq^T + bq) * c
  gemm_bt<1><<<dim3(8, 64), 256, 0, stream>>>(qb, Wb + 2097152, out, bq, nullptr, cval, 1024);
}

// Round 4
// 91.039 us; speedup vs baseline: 1.5382x; 1.5382x over previous
//
#include <hip/hip_runtime.h>
#include <hip/hip_bf16.h>
#include <stdint.h>

typedef __bf16 bf16_t;
typedef __bf16 bf16x8 __attribute__((ext_vector_type(8)));
typedef float f32x4 __attribute__((ext_vector_type(4)));

#define E_DIM 1024
#define S_DIM 8192

// ---- global -> LDS direct load, 16 B per lane ----
__device__ __forceinline__ void gload_lds16(const void* g, void* l) {
  using gptr_t = const __attribute__((address_space(1))) void*;
  using lptr_t = __attribute__((address_space(3))) void*;
  gptr_t gp = (gptr_t)(uintptr_t)g;
  lptr_t lp = (lptr_t)(uint32_t)(uintptr_t)l;
  __builtin_amdgcn_global_load_lds(gp, lp, 16, 0, 0);
}

__device__ __forceinline__ void cvt8(const float* __restrict__ src,
                                     bf16_t* __restrict__ dst, int i) {
  const float4* s = reinterpret_cast<const float4*>(src) + (size_t)i * 2;
  float4 a = s[0], b = s[1];
  bf16x8 o;
  o[0] = (bf16_t)a.x; o[1] = (bf16_t)a.y; o[2] = (bf16_t)a.z; o[3] = (bf16_t)a.w;
  o[4] = (bf16_t)b.x; o[5] = (bf16_t)b.y; o[6] = (bf16_t)b.z; o[7] = (bf16_t)b.w;
  *reinterpret_cast<bf16x8*>(dst + (size_t)i * 8) = o;
}

// one launch converts q, Wk, Wv, Wq -> bf16
__global__ __launch_bounds__(256) void cvt_all(const float* __restrict__ q,
                                               const float* __restrict__ Wk,
                                               const float* __restrict__ Wv,
                                               const float* __restrict__ Wq,
                                               bf16_t* __restrict__ qb,
                                               bf16_t* __restrict__ Wb) {
  const int b = blockIdx.x;
  const int t = threadIdx.x;
  if (b < 4096) {
    cvt8(q, qb, b * 256 + t);               // 1048576 chunks of 8
  } else if (b < 4608) {
    cvt8(Wk, Wb, (b - 4096) * 256 + t);     // 131072 chunks
  } else if (b < 5120) {
    cvt8(Wv, Wb + 1048576, (b - 4608) * 256 + t);
  } else {
    cvt8(Wq, Wb + 2097152, (b - 5120) * 256 + t);
  }
}

// ---- fused K/V GEMM + column-softmax partial reduction ----
// A:[8192][1024] bf16, Wk/Wv:[1024][1024] bf16 (row-major, output col = W row)
// For block (bx,by): rows m0..m0+127, cols n0..n0+127.
// Computes K=A*Wk^T+bk, V=A*Wv^T+bv tiles in-register, then
// pden[by][col] = sum_rows exp(K), pnum[by][col] = sum_rows exp(K)*V.
__global__ __launch_bounds__(256, 2) void gemm_kv(const bf16_t* __restrict__ A,
                                                  const bf16_t* __restrict__ Wk,
                                                  const bf16_t* __restrict__ Wv,
                                                  const float* __restrict__ bk,
                                                  const float* __restrict__ bv,
                                                  float* __restrict__ pden,
                                                  float* __restrict__ pnum) {
  __shared__ bf16_t lA[128 * 32];
  __shared__ bf16_t lK[128 * 32];
  __shared__ bf16_t lV[128 * 32];
  __shared__ float sden[2][128];
  __shared__ float snum[2][128];

  const int tid = threadIdx.x;
  const int wv = tid >> 6;
  const int lane = tid & 63;
  const int m0 = blockIdx.y * 128;
  const int n0 = blockIdx.x * 128;
  const int wr = wv >> 1;
  const int wc = wv & 1;

  f32x4 accK[4][4], accV[4][4];
#pragma unroll
  for (int i = 0; i < 4; ++i)
#pragma unroll
    for (int j = 0; j < 4; ++j) {
      accK[i][j] = (f32x4){0.f, 0.f, 0.f, 0.f};
      accV[i][j] = (f32x4){0.f, 0.f, 0.f, 0.f};
    }

  const int srow = wv * 16 + (lane >> 2);
  const int skk = (lane & 3) * 8;
  const bf16_t* gA0 = A + (size_t)(m0 + srow) * E_DIM + skk;
  const bf16_t* gA1 = gA0 + (size_t)64 * E_DIM;
  const bf16_t* gK0 = Wk + (size_t)(n0 + srow) * E_DIM + skk;
  const bf16_t* gK1 = gK0 + (size_t)64 * E_DIM;
  const bf16_t* gV0 = Wv + (size_t)(n0 + srow) * E_DIM + skk;
  const bf16_t* gV1 = gV0 + (size_t)64 * E_DIM;
  bf16_t* lA0 = &lA[wv * 512];
  bf16_t* lA1 = &lA[(wv + 4) * 512];
  bf16_t* lK0 = &lK[wv * 512];
  bf16_t* lK1 = &lK[(wv + 4) * 512];
  bf16_t* lV0 = &lV[wv * 512];
  bf16_t* lV1 = &lV[(wv + 4) * 512];

  const int frow = lane & 15;
  const int fk = (lane >> 4) * 8;

  for (int k0 = 0; k0 < E_DIM; k0 += 32) {
    gload_lds16(gA0 + k0, lA0);
    gload_lds16(gA1 + k0, lA1);
    gload_lds16(gK0 + k0, lK0);
    gload_lds16(gK1 + k0, lK1);
    gload_lds16(gV0 + k0, lV0);
    gload_lds16(gV1 + k0, lV1);
    __syncthreads();

    bf16x8 af[4], kf[4], vf[4];
#pragma unroll
    for (int m = 0; m < 4; ++m)
      af[m] = *reinterpret_cast<const bf16x8*>(&lA[(wr * 64 + m * 16 + frow) * 32 + fk]);
#pragma unroll
    for (int n = 0; n < 4; ++n) {
      kf[n] = *reinterpret_cast<const bf16x8*>(&lK[(wc * 64 + n * 16 + frow) * 32 + fk]);
      vf[n] = *reinterpret_cast<const bf16x8*>(&lV[(wc * 64 + n * 16 + frow) * 32 + fk]);
    }
#pragma unroll
    for (int m = 0; m < 4; ++m)
#pragma unroll
      for (int n = 0; n < 4; ++n) {
        accK[m][n] = __builtin_amdgcn_mfma_f32_16x16x32_bf16(af[m], kf[n], accK[m][n], 0, 0, 0);
        accV[m][n] = __builtin_amdgcn_mfma_f32_16x16x32_bf16(af[m], vf[n], accV[m][n], 0, 0, 0);
      }
    __syncthreads();
  }

  // ---- epilogue: per-column exp-reduction over this block's 128 rows ----
  const int ccol = lane & 15;
#pragma unroll
  for (int n = 0; n < 4; ++n) {
    const int col = n0 + wc * 64 + n * 16 + ccol;
    const float bkc = bk[col];
    const float bvc = bv[col];
    float dp = 0.f, np = 0.f;
#pragma unroll
    for (int m = 0; m < 4; ++m)
#pragma unroll
      for (int r = 0; r < 4; ++r) {
        float e = __expf(accK[m][n][r] + bkc);
        dp += e;
        np += e * (accV[m][n][r] + bvc);
      }
    // sum the 4 row-groups (lanes l, l+16, l+32, l+48 share a column)
    dp += __shfl_xor(dp, 16); dp += __shfl_xor(dp, 32);
    np += __shfl_xor(np, 16); np += __shfl_xor(np, 32);
    if (lane < 16) {
      sden[wr][wc * 64 + n * 16 + lane] = dp;
      snum[wr][wc * 64 + n * 16 + lane] = np;
    }
  }
  __syncthreads();
  if (tid < 128) {
    float d = sden[0][tid] + sden[1][tid];
    float nm = snum[0][tid] + snum[1][tid];
    pden[(size_t)blockIdx.y * 1024 + n0 + tid] = d;
    pnum[(size_t)blockIdx.y * 1024 + n0 + tid] = nm;
  }
}

// ---- finalize: c = sum_f (sum_b pnum) / (sum_b pden), single block ----
__global__ __launch_bounds__(1024) void finalize(const float* __restrict__ pden,
                                                 const float* __restrict__ pnum,
                                                 float* __restrict__ cval) {
  const int t = threadIdx.x;
  float d = 0.f, nm = 0.f;
  for (int b = 0; b < 64; ++b) {
    d += pden[b * 1024 + t];
    nm += pnum[b * 1024 + t];
  }
  float val = nm / d;
  __shared__ float red[1024];
  red[t] = val;
  __syncthreads();
  for (int s = 512; s > 0; s >>= 1) {
    if (t < s) red[t] += red[t + s];
    __syncthreads();
  }
  if (t == 0) cval[0] = red[0];
}

// ---- Q GEMM with fused sigmoid*c epilogue ----
__global__ __launch_bounds__(256) void gemm_q(const bf16_t* __restrict__ A,
                                              const bf16_t* __restrict__ B,
                                              float* __restrict__ C,
                                              const float* __restrict__ bias,
                                              const float* __restrict__ cptr) {
  __shared__ bf16_t lA[128 * 32];
  __shared__ bf16_t lB[128 * 32];

  const int tid = threadIdx.x;
  const int wv = tid >> 6;
  const int lane = tid & 63;
  const int m0 = blockIdx.y * 128;
  const int n0 = blockIdx.x * 128;
  const int wr = wv >> 1;
  const int wc = wv & 1;

  f32x4 acc[4][4];
#pragma unroll
  for (int i = 0; i < 4; ++i)
#pragma unroll
    for (int j = 0; j < 4; ++j) acc[i][j] = (f32x4){0.f, 0.f, 0.f, 0.f};

  const int srow = wv * 16 + (lane >> 2);
  const int skk = (lane & 3) * 8;
  const bf16_t* gA0 = A + (size_t)(m0 + srow) * E_DIM + skk;
  const bf16_t* gA1 = gA0 + (size_t)64 * E_DIM;
  const bf16_t* gB0 = B + (size_t)(n0 + srow) * E_DIM + skk;
  const bf16_t* gB1 = gB0 + (size_t)64 * E_DIM;
  bf16_t* lA0 = &lA[wv * 512];
  bf16_t* lA1 = &lA[(wv + 4) * 512];
  bf16_t* lB0 = &lB[wv * 512];
  bf16_t* lB1 = &lB[(wv + 4) * 512];

  const int frow = lane & 15;
  const int fk = (lane >> 4) * 8;

  for (int k0 = 0; k0 < E_DIM; k0 += 32) {
    gload_lds16(gA0 + k0, lA0);
    gload_lds16(gA1 + k0, lA1);
    gload_lds16(gB0 + k0, lB0);
    gload_lds16(gB1 + k0, lB1);
    __syncthreads();

    bf16x8 af[4], bfr[4];
#pragma unroll
    for (int m = 0; m < 4; ++m)
      af[m] = *reinterpret_cast<const bf16x8*>(&lA[(wr * 64 + m * 16 + frow) * 32 + fk]);
#pragma unroll
    for (int n = 0; n < 4; ++n)
      bfr[n] = *reinterpret_cast<const bf16x8*>(&lB[(wc * 64 + n * 16 + frow) * 32 + fk]);
#pragma unroll
    for (int m = 0; m < 4; ++m)
#pragma unroll
      for (int n = 0; n < 4; ++n)
        acc[m][n] = __builtin_amdgcn_mfma_f32_16x16x32_bf16(af[m], bfr[n], acc[m][n], 0, 0, 0);
    __syncthreads();
  }

  const float cv = cptr[0];
  const int crow = (lane >> 4) * 4;
  const int ccol = lane & 15;
#pragma unroll
  for (int n = 0; n < 4; ++n) {
    const int col = n0 + wc * 64 + n * 16 + ccol;
    const float bs = bias[col];
#pragma unroll
    for (int m = 0; m < 4; ++m) {
      const int row = m0 + wr * 64 + m * 16 + crow;
#pragma unroll
      for (int r = 0; r < 4; ++r) {
        float v = acc[m][n][r] + bs;
        v = cv / (1.f + __expf(-v));
        C[(size_t)(row + r) * 1024 + col] = v;
      }
    }
  }
}

extern "C" void kernel_launch(void* const* d_in, const int* in_sizes, int n_in,
                              void* d_out, int out_size, void* d_ws, size_t ws_size,
                              hipStream_t stream) {
  const float* q = (const float*)d_in[0];
  const float* Wq = (const float*)d_in[1];
  const float* bq = (const float*)d_in[2];
  const float* Wk = (const float*)d_in[3];
  const float* bk = (const float*)d_in[4];
  const float* Wv = (const float*)d_in[5];
  const float* bv = (const float*)d_in[6];
  float* out = (float*)d_out;

  char* ws = (char*)d_ws;
  bf16_t* qb = (bf16_t*)ws;                                  // 16 MB
  bf16_t* Wb = (bf16_t*)(ws + (size_t)16 * 1024 * 1024);     // 6 MB [Wk;Wv;Wq]
  float* pden = (float*)(ws + (size_t)24 * 1024 * 1024);     // 256 KB
  float* pnum = pden + 64 * 1024;                            // 256 KB
  float* cval = pnum + 64 * 1024;

  cvt_all<<<5632, 256, 0, stream>>>(q, Wk, Wv, Wq, qb, Wb);
  gemm_kv<<<dim3(8, 64), 256, 0, stream>>>(qb, Wb, Wb + 1048576, bk, bv, pden, pnum);
  finalize<<<1, 1024, 0, stream>>>(pden, pnum, cval);
  gemm_q<<<dim3(8, 64), 256, 0, stream>>>(qb, Wb + 2097152, out, bq, cval);
}

// Round 5
// 77.841 us; speedup vs baseline: 1.7990x; 1.1695x over previous
//
#include <hip/hip_runtime.h>
#include <hip/hip_bf16.h>
#include <stdint.h>

typedef __bf16 bf16_t;
typedef __bf16 bf16x8 __attribute__((ext_vector_type(8)));
typedef float f32x4 __attribute__((ext_vector_type(4)));

#define NKT 16  // K-tiles: 1024 / 64

// ---- global -> LDS direct load, 16 B per lane (dest = wave-uniform base + lane*16) ----
__device__ __forceinline__ void gload_lds16(const void* g, void* l) {
  using gptr_t = const __attribute__((address_space(1))) void*;
  using lptr_t = __attribute__((address_space(3))) void*;
  gptr_t gp = (gptr_t)(uintptr_t)g;
  lptr_t lp = (lptr_t)(uint32_t)(uintptr_t)l;
  __builtin_amdgcn_global_load_lds(gp, lp, 16, 0, 0);
}

__device__ __forceinline__ bf16x8 cvt8v(const float* __restrict__ src, int i8) {
  const float4* s = reinterpret_cast<const float4*>(src) + (size_t)i8 * 2;
  float4 a = s[0], b = s[1];
  bf16x8 o;
  o[0] = (bf16_t)a.x; o[1] = (bf16_t)a.y; o[2] = (bf16_t)a.z; o[3] = (bf16_t)a.w;
  o[4] = (bf16_t)b.x; o[5] = (bf16_t)b.y; o[6] = (bf16_t)b.z; o[7] = (bf16_t)b.w;
  return o;
}

// converts q->qb, Wk/Wv -> interleaved Wkv (row 2j = Wk_j, row 2j+1 = Wv_j),
// Wq->Wqb, bk/bv -> interleaved bkv
__global__ __launch_bounds__(256) void cvt_all(const float* __restrict__ q,
                                               const float* __restrict__ Wk,
                                               const float* __restrict__ Wv,
                                               const float* __restrict__ Wq,
                                               const float* __restrict__ bk,
                                               const float* __restrict__ bv,
                                               bf16_t* __restrict__ qb,
                                               bf16_t* __restrict__ Wkv,
                                               bf16_t* __restrict__ Wqb,
                                               float* __restrict__ bkv) {
  const int b = blockIdx.x;
  const int t = threadIdx.x;
  if (b < 4096) {
    int i = b * 256 + t;
    *reinterpret_cast<bf16x8*>(qb + (size_t)i * 8) = cvt8v(q, i);
  } else if (b < 4608) {
    int i = (b - 4096) * 256 + t;            // [0, 131072)
    int j = i >> 7, c8 = i & 127;            // row j, col-chunk c8
    *reinterpret_cast<bf16x8*>(Wkv + (size_t)j * 2048 + c8 * 8) = cvt8v(Wk, i);
  } else if (b < 5120) {
    int i = (b - 4608) * 256 + t;
    int j = i >> 7, c8 = i & 127;
    *reinterpret_cast<bf16x8*>(Wkv + (size_t)j * 2048 + 1024 + c8 * 8) = cvt8v(Wv, i);
  } else if (b < 5632) {
    int i = (b - 5120) * 256 + t;
    *reinterpret_cast<bf16x8*>(Wqb + (size_t)i * 8) = cvt8v(Wq, i);
  } else {
#pragma unroll
    for (int u = 0; u < 4; ++u) {
      int j = t * 4 + u;
      bkv[2 * j] = bk[j];
      bkv[2 * j + 1] = bv[j];
    }
  }
}

// ======================= fused KV GEMM (8-wave, counted-vmcnt) =======================
// A: qb [8192][1024], Bkv: interleaved [2048][1024]. BM=256, BN=256, BK=64.
// grid 256 (32 m-blocks x 8 n-blocks), 512 threads = 8 waves (2M x 4N).
// Epilogue: column-pair exp-reduction -> pden/pnum[32][1024].
__global__ __launch_bounds__(512, 1) void gemm_kv8(const bf16_t* __restrict__ A,
                                                   const bf16_t* __restrict__ Bkv,
                                                   const float* __restrict__ bkv,
                                                   float* __restrict__ pden,
                                                   float* __restrict__ pnum) {
  __shared__ bf16_t lA[2 * 256 * 64];
  __shared__ bf16_t lB[2 * 256 * 64];
  __shared__ float sD[2][128];
  __shared__ float sN[2][128];

  const int tid = threadIdx.x;
  const int w = tid >> 6, l = tid & 63;
  const int wr = w >> 2, wc = w & 3;           // 2M x 4N waves
  const int swz = (blockIdx.x & 7) * 32 + (blockIdx.x >> 3);  // XCD chunking (256%8==0)
  const int bx = swz & 7, by = swz >> 3;
  const int m0 = by * 256, n0 = bx * 256;

  // staging lane constants: lane covers row (+rl3), source chunk pre-swizzled
  const int rl3 = l >> 3;
  const int scol = ((l & 7) ^ rl3) * 8;        // source elem offset in 64-k window
  // frag lane constants
  const int fr = l & 15, fg = l >> 4, sw = l & 7;

  const bf16_t* Ab = A + (size_t)(m0 + w * 8 + rl3) * 1024 + scol;
  const bf16_t* Bb = Bkv + (size_t)(n0 + w * 8 + rl3) * 1024 + scol;

  f32x4 acc[8][4];
#pragma unroll
  for (int m = 0; m < 8; ++m)
#pragma unroll
    for (int n = 0; n < 4; ++n) acc[m][n] = (f32x4){0.f, 0.f, 0.f, 0.f};

#define STAGE_A(kt, h, r, slot)                                              \
  gload_lds16(Ab + (size_t)((h) * 128 + (r) * 64) * 1024 + (kt) * 64,        \
              &lA[(slot) * 16384 + ((h) * 128 + (r) * 64 + w * 8) * 64])
#define STAGE_B(kt, h, r, slot)                                              \
  gload_lds16(Bb + (size_t)((h) * 128 + (r) * 64) * 1024 + (kt) * 64,        \
              &lB[(slot) * 16384 + ((h) * 128 + (r) * 64 + w * 8) * 64])
#define RD_A(mm, ks) \
  (*reinterpret_cast<const bf16x8*>(&lA[aBase + ((mm) * 16 + fr) * 64 + ((((ks) * 4) + fg) ^ sw) * 8]))
#define RD_B(nn, ks) \
  (*reinterpret_cast<const bf16x8*>(&lB[bBase + ((nn) * 16 + fr) * 64 + ((((ks) * 4) + fg) ^ sw) * 8]))

  // prologue: stage tile 0 (8 loads, order: ha0,ha1,hb0,hb1 x 2 rounds)
  STAGE_A(0, 0, 0, 0); STAGE_A(0, 0, 1, 0); STAGE_A(0, 1, 0, 0); STAGE_A(0, 1, 1, 0);
  STAGE_B(0, 0, 0, 0); STAGE_B(0, 0, 1, 0); STAGE_B(0, 1, 0, 0); STAGE_B(0, 1, 1, 0);

#pragma unroll 1
  for (int T = 0; T < NKT; ++T) {
    const int slot = T & 1, ns = slot ^ 1;
    const bool pf = (T + 1) < NKT;
    if (pf) { STAGE_A(T + 1, 0, 0, ns); STAGE_A(T + 1, 0, 1, ns); }
    if (pf) asm volatile("s_waitcnt vmcnt(2)" ::: "memory");
    else    asm volatile("s_waitcnt vmcnt(0)" ::: "memory");
    __builtin_amdgcn_s_barrier();
    __builtin_amdgcn_sched_barrier(0);

    const int aBase = slot * 16384 + wr * 8192;
    const int bBase = slot * 16384 + wc * 4096;
    bf16x8 af[4], bfv[4];
    // ---- phase 1: ks=0, m 0..3 (+ all B ks0) ----
#pragma unroll
    for (int n = 0; n < 4; ++n) bfv[n] = RD_B(n, 0);
#pragma unroll
    for (int m = 0; m < 4; ++m) af[m] = RD_A(m, 0);
    if (pf) { STAGE_A(T + 1, 1, 0, ns); STAGE_A(T + 1, 1, 1, ns); }
    __builtin_amdgcn_s_setprio(1);
#pragma unroll
    for (int m = 0; m < 4; ++m)
#pragma unroll
      for (int n = 0; n < 4; ++n)
        acc[m][n] = __builtin_amdgcn_mfma_f32_16x16x32_bf16(af[m], bfv[n], acc[m][n], 0, 0, 0);
    __builtin_amdgcn_s_setprio(0);
    __builtin_amdgcn_s_barrier();
    __builtin_amdgcn_sched_barrier(0);
    // ---- phase 2: ks=0, m 4..7 ----
#pragma unroll
    for (int m = 0; m < 4; ++m) af[m] = RD_A(m + 4, 0);
    if (pf) { STAGE_B(T + 1, 0, 0, ns); STAGE_B(T + 1, 0, 1, ns); }
    __builtin_amdgcn_s_setprio(1);
#pragma unroll
    for (int m = 0; m < 4; ++m)
#pragma unroll
      for (int n = 0; n < 4; ++n)
        acc[m + 4][n] = __builtin_amdgcn_mfma_f32_16x16x32_bf16(af[m], bfv[n], acc[m + 4][n], 0, 0, 0);
    __builtin_amdgcn_s_setprio(0);
    __builtin_amdgcn_s_barrier();
    __builtin_amdgcn_sched_barrier(0);
    // ---- phase 3: ks=1, m 0..3 (+ all B ks1) ----
#pragma unroll
    for (int n = 0; n < 4; ++n) bfv[n] = RD_B(n, 1);
#pragma unroll
    for (int m = 0; m < 4; ++m) af[m] = RD_A(m, 1);
    if (pf) { STAGE_B(T + 1, 1, 0, ns); STAGE_B(T + 1, 1, 1, ns); }
    __builtin_amdgcn_s_setprio(1);
#pragma unroll
    for (int m = 0; m < 4; ++m)
#pragma unroll
      for (int n = 0; n < 4; ++n)
        acc[m][n] = __builtin_amdgcn_mfma_f32_16x16x32_bf16(af[m], bfv[n], acc[m][n], 0, 0, 0);
    __builtin_amdgcn_s_setprio(0);
    __builtin_amdgcn_s_barrier();
    __builtin_amdgcn_sched_barrier(0);
    // ---- phase 4: ks=1, m 4..7 ----
#pragma unroll
    for (int m = 0; m < 4; ++m) af[m] = RD_A(m + 4, 1);
    __builtin_amdgcn_s_setprio(1);
#pragma unroll
    for (int m = 0; m < 4; ++m)
#pragma unroll
      for (int n = 0; n < 4; ++n)
        acc[m + 4][n] = __builtin_amdgcn_mfma_f32_16x16x32_bf16(af[m], bfv[n], acc[m + 4][n], 0, 0, 0);
    __builtin_amdgcn_s_setprio(0);
    __builtin_amdgcn_s_barrier();
    __builtin_amdgcn_sched_barrier(0);
  }

  // ---- epilogue: per column-pair exp reduction over this block's 256 rows ----
  float dpn[4] = {0.f, 0.f, 0.f, 0.f};
  float npn[4] = {0.f, 0.f, 0.f, 0.f};
#pragma unroll
  for (int n = 0; n < 4; ++n) {
    const int col = n0 + wc * 64 + n * 16 + fr;
    const float bc = bkv[col];
#pragma unroll
    for (int m = 0; m < 8; ++m)
#pragma unroll
      for (int r = 0; r < 4; ++r) {
        float x = acc[m][n][r] + bc;
        float xp = __shfl_xor(x, 1);       // partner column (V for even lanes)
        float e = __expf(x);
        dpn[n] += e;
        npn[n] += e * xp;
      }
    dpn[n] += __shfl_xor(dpn[n], 16); dpn[n] += __shfl_xor(dpn[n], 32);
    npn[n] += __shfl_xor(npn[n], 16); npn[n] += __shfl_xor(npn[n], 32);
  }
  if (l < 16 && (l & 1) == 0) {
#pragma unroll
    for (int n = 0; n < 4; ++n) {
      sD[wr][wc * 32 + n * 8 + (l >> 1)] = dpn[n];
      sN[wr][wc * 32 + n * 8 + (l >> 1)] = npn[n];
    }
  }
  __syncthreads();
  if (tid < 128) {
    pden[(size_t)by * 1024 + bx * 128 + tid] = sD[0][tid] + sD[1][tid];
    pnum[(size_t)by * 1024 + bx * 128 + tid] = sN[0][tid] + sN[1][tid];
  }
#undef STAGE_A
#undef STAGE_B
#undef RD_A
#undef RD_B
}

// ---- finalize: c = sum_f (sum_by pnum) / (sum_by pden) ----
__global__ __launch_bounds__(1024) void finalize(const float* __restrict__ pden,
                                                 const float* __restrict__ pnum,
                                                 float* __restrict__ cval) {
  const int t = threadIdx.x;
  float d = 0.f, nm = 0.f;
  for (int b = 0; b < 32; ++b) {
    d += pden[b * 1024 + t];
    nm += pnum[b * 1024 + t];
  }
  float val = nm / d;
  __shared__ float red[1024];
  red[t] = val;
  __syncthreads();
  for (int s = 512; s > 0; s >>= 1) {
    if (t < s) red[t] += red[t + s];
    __syncthreads();
  }
  if (t == 0) cval[0] = red[0];
}

// ======================= Q GEMM (8-wave, counted-vmcnt) =======================
// BM=256, BN=128, BK=64. grid 256 (32 m x 8 n), 8 waves as 4M x 2N.
// Epilogue: out = cval * sigmoid(acc + bq).
__global__ __launch_bounds__(512, 1) void gemm_q8(const bf16_t* __restrict__ A,
                                                  const bf16_t* __restrict__ Bq,
                                                  const float* __restrict__ bias,
                                                  const float* __restrict__ cptr,
                                                  float* __restrict__ C) {
  __shared__ bf16_t lA[2 * 256 * 64];
  __shared__ bf16_t lB[2 * 128 * 64];

  const int tid = threadIdx.x;
  const int w = tid >> 6, l = tid & 63;
  const int wr = w >> 1, wc = w & 1;           // 4M x 2N waves
  const int swz = (blockIdx.x & 7) * 32 + (blockIdx.x >> 3);
  const int bx = swz & 7, by = swz >> 3;
  const int m0 = by * 256, n0 = bx * 128;

  const int rl3 = l >> 3;
  const int scol = ((l & 7) ^ rl3) * 8;
  const int fr = l & 15, fg = l >> 4, sw = l & 7;

  const bf16_t* Ab = A + (size_t)(m0 + w * 8 + rl3) * 1024 + scol;
  const bf16_t* Bb = Bq + (size_t)(n0 + w * 8 + rl3) * 1024 + scol;

  f32x4 acc[4][4];
#pragma unroll
  for (int m = 0; m < 4; ++m)
#pragma unroll
    for (int n = 0; n < 4; ++n) acc[m][n] = (f32x4){0.f, 0.f, 0.f, 0.f};

#define STAGE_A(kt, h, r, slot)                                              \
  gload_lds16(Ab + (size_t)((h) * 128 + (r) * 64) * 1024 + (kt) * 64,        \
              &lA[(slot) * 16384 + ((h) * 128 + (r) * 64 + w * 8) * 64])
#define STAGE_B(kt, h, slot)                                                 \
  gload_lds16(Bb + (size_t)((h) * 64) * 1024 + (kt) * 64,                    \
              &lB[(slot) * 8192 + ((h) * 64 + w * 8) * 64])
#define RD_A(mm, ks) \
  (*reinterpret_cast<const bf16x8*>(&lA[aBase + ((mm) * 16 + fr) * 64 + ((((ks) * 4) + fg) ^ sw) * 8]))
#define RD_B(nn, ks) \
  (*reinterpret_cast<const bf16x8*>(&lB[bBase + ((nn) * 16 + fr) * 64 + ((((ks) * 4) + fg) ^ sw) * 8]))

  // prologue: tile 0 (6 loads)
  STAGE_A(0, 0, 0, 0); STAGE_A(0, 0, 1, 0); STAGE_A(0, 1, 0, 0); STAGE_A(0, 1, 1, 0);
  STAGE_B(0, 0, 0); STAGE_B(0, 1, 0);

#pragma unroll 1
  for (int T = 0; T < NKT; ++T) {
    const int slot = T & 1, ns = slot ^ 1;
    const bool pf = (T + 1) < NKT;
    if (pf) { STAGE_A(T + 1, 0, 0, ns); STAGE_A(T + 1, 0, 1, ns); }
    if (pf) asm volatile("s_waitcnt vmcnt(2)" ::: "memory");
    else    asm volatile("s_waitcnt vmcnt(0)" ::: "memory");
    __builtin_amdgcn_s_barrier();
    __builtin_amdgcn_sched_barrier(0);

    const int aBase = slot * 16384 + wr * 4096;   // wr*64 rows * 64
    const int bBase = slot * 8192 + wc * 4096;    // wc*64 rows * 64
    bf16x8 af[2], bfv[4];
    // ---- phase 1: ks=0, m 0..1 (+ all B ks0) ----
#pragma unroll
    for (int n = 0; n < 4; ++n) bfv[n] = RD_B(n, 0);
    af[0] = RD_A(0, 0); af[1] = RD_A(1, 0);
    if (pf) { STAGE_A(T + 1, 1, 0, ns); STAGE_A(T + 1, 1, 1, ns); }
    __builtin_amdgcn_s_setprio(1);
#pragma unroll
    for (int m = 0; m < 2; ++m)
#pragma unroll
      for (int n = 0; n < 4; ++n)
        acc[m][n] = __builtin_amdgcn_mfma_f32_16x16x32_bf16(af[m], bfv[n], acc[m][n], 0, 0, 0);
    __builtin_amdgcn_s_setprio(0);
    __builtin_amdgcn_s_barrier();
    __builtin_amdgcn_sched_barrier(0);
    // ---- phase 2: ks=0, m 2..3 ----
    af[0] = RD_A(2, 0); af[1] = RD_A(3, 0);
    if (pf) STAGE_B(T + 1, 0, ns);
    __builtin_amdgcn_s_setprio(1);
#pragma unroll
    for (int m = 0; m < 2; ++m)
#pragma unroll
      for (int n = 0; n < 4; ++n)
        acc[m + 2][n] = __builtin_amdgcn_mfma_f32_16x16x32_bf16(af[m], bfv[n], acc[m + 2][n], 0, 0, 0);
    __builtin_amdgcn_s_setprio(0);
    __builtin_amdgcn_s_barrier();
    __builtin_amdgcn_sched_barrier(0);
    // ---- phase 3: ks=1, m 0..1 (+ all B ks1) ----
#pragma unroll
    for (int n = 0; n < 4; ++n) bfv[n] = RD_B(n, 1);
    af[0] = RD_A(0, 1); af[1] = RD_A(1, 1);
    if (pf) STAGE_B(T + 1, 1, ns);
    __builtin_amdgcn_s_setprio(1);
#pragma unroll
    for (int m = 0; m < 2; ++m)
#pragma unroll
      for (int n = 0; n < 4; ++n)
        acc[m][n] = __builtin_amdgcn_mfma_f32_16x16x32_bf16(af[m], bfv[n], acc[m][n], 0, 0, 0);
    __builtin_amdgcn_s_setprio(0);
    __builtin_amdgcn_s_barrier();
    __builtin_amdgcn_sched_barrier(0);
    // ---- phase 4: ks=1, m 2..3 ----
    af[0] = RD_A(2, 1); af[1] = RD_A(3, 1);
    __builtin_amdgcn_s_setprio(1);
#pragma unroll
    for (int m = 0; m < 2; ++m)
#pragma unroll
      for (int n = 0; n < 4; ++n)
        acc[m + 2][n] = __builtin_amdgcn_mfma_f32_16x16x32_bf16(af[m], bfv[n], acc[m + 2][n], 0, 0, 0);
    __builtin_amdgcn_s_setprio(0);
    __builtin_amdgcn_s_barrier();
    __builtin_amdgcn_sched_barrier(0);
  }

  const float cv = cptr[0];
#pragma unroll
  for (int n = 0; n < 4; ++n) {
    const int col = n0 + wc * 64 + n * 16 + fr;
    const float bs = bias[col];
#pragma unroll
    for (int m = 0; m < 4; ++m) {
      const int row = m0 + wr * 64 + m * 16 + fg * 4;
#pragma unroll
      for (int r = 0; r < 4; ++r) {
        float v = acc[m][n][r] + bs;
        v = cv / (1.f + __expf(-v));
        C[(size_t)(row + r) * 1024 + col] = v;
      }
    }
  }
#undef STAGE_A
#undef STAGE_B
#undef RD_A
#undef RD_B
}

extern "C" void kernel_launch(void* const* d_in, const int* in_sizes, int n_in,
                              void* d_out, int out_size, void* d_ws, size_t ws_size,
                              hipStream_t stream) {
  const float* q = (const float*)d_in[0];
  const float* Wq = (const float*)d_in[1];
  const float* bq = (const float*)d_in[2];
  const float* Wk = (const float*)d_in[3];
  const float* bk = (const float*)d_in[4];
  const float* Wv = (const float*)d_in[5];
  const float* bv = (const float*)d_in[6];
  float* out = (float*)d_out;

  char* ws = (char*)d_ws;
  bf16_t* qb = (bf16_t*)ws;                                  // 16 MB
  bf16_t* Wkv = (bf16_t*)(ws + (size_t)16 * 1024 * 1024);    // 4 MB interleaved
  bf16_t* Wqb = (bf16_t*)(ws + (size_t)20 * 1024 * 1024);    // 2 MB
  float* bkv = (float*)(ws + (size_t)22 * 1024 * 1024);      // 8 KB
  float* pden = (float*)(ws + (size_t)23 * 1024 * 1024);     // 128 KB
  float* pnum = (float*)(ws + (size_t)23 * 1024 * 1024 + 131072);
  float* cval = (float*)(ws + (size_t)23 * 1024 * 1024 + 262144);

  cvt_all<<<5633, 256, 0, stream>>>(q, Wk, Wv, Wq, bk, bv, qb, Wkv, Wqb, bkv);
  gemm_kv8<<<256, 512, 0, stream>>>(qb, Wkv, bkv, pden, pnum);
  finalize<<<1, 1024, 0, stream>>>(pden, pnum, cval);
  gemm_q8<<<256, 512, 0, stream>>>(qb, Wqb, bq, cval, out);
}